// Round 1
// baseline (637.066 us; speedup 1.0000x reference)
//
#include <hip/hip_runtime.h>
#include <math.h>

#define TPC 225
#define NCLS 224
#define NHID 1024
#define BATCH 2048
#define CAP 256  // bucket capacity per class (max realistic count ~30 at lambda=9.1)

// ---------------------------------------------------------------------------
// Kernel 1: bucket examples by class. Single block, LDS atomics.
// bucket[c*CAP + i] = (word << 16) | row
// ---------------------------------------------------------------------------
__global__ __launch_bounds__(256) void hs_bucket(const int* __restrict__ labels,
                                                 int* __restrict__ bucket,
                                                 int* __restrict__ cnt) {
    __shared__ int scnt[NCLS];
    const int t = threadIdx.x;
    for (int i = t; i < NCLS; i += 256) scnt[i] = 0;
    __syncthreads();
    for (int b = t; b < BATCH; b += 256) {
        int lab = labels[b];
        int c = lab / TPC;
        int w = lab - c * TPC;
        int pos = atomicAdd(&scnt[c], 1);
        bucket[c * CAP + pos] = (w << 16) | b;
    }
    __syncthreads();
    for (int i = t; i < NCLS; i += 256) cnt[i] = scnt[i];
}

// ---------------------------------------------------------------------------
// Shared helpers: double-buffered W loads + register-tile FMA.
// k-slot mapping: thread (lane) owns columns k = lane + 64*j, j in 0..3
// (256 slots; tail slots clamped and masked at softmax time).
// ---------------------------------------------------------------------------
__device__ __forceinline__ void load_w4(float w[4][4], const float* __restrict__ wp,
                                        const int kc[4], const int stride) {
#pragma unroll
    for (int dd = 0; dd < 4; dd++)
#pragma unroll
        for (int j = 0; j < 4; j++)
            w[dd][j] = wp[dd * stride + kc[j]];
}

__device__ __forceinline__ void fma4x4(float acc[4][4], const float* __restrict__ xsb,
                                       const int off, const float w[4][4]) {
    float4 xv[4];
#pragma unroll
    for (int i = 0; i < 4; i++)
        xv[i] = *(const float4*)(xsb + i * NHID + off);
#pragma unroll
    for (int dd = 0; dd < 4; dd++)
#pragma unroll
        for (int i = 0; i < 4; i++) {
            float xvv = ((const float*)&xv[i])[dd];
#pragma unroll
            for (int j = 0; j < 4; j++)
                acc[i][j] = fmaf(xvv, w[dd][j], acc[i][j]);
        }
}

__device__ __forceinline__ void fma2x4(float acc[2][4], const float* __restrict__ xsb,
                                       const int off, const float w[4][4]) {
    float4 xa = *(const float4*)(xsb + off);
    float4 xb = *(const float4*)(xsb + NHID + off);
#pragma unroll
    for (int dd = 0; dd < 4; dd++) {
        float xav = ((const float*)&xa)[dd];
        float xbv = ((const float*)&xb)[dd];
#pragma unroll
        for (int j = 0; j < 4; j++) {
            acc[0][j] = fmaf(xav, w[dd][j], acc[0][j]);
            acc[1][j] = fmaf(xbv, w[dd][j], acc[1][j]);
        }
    }
}

// ---------------------------------------------------------------------------
// Kernel 2: top level. 256 blocks x 8 rows. Fused GEMM + softmax -> p_cls.
// W_top is [NHID][NCLS] row-major; k consecutive across lanes = coalesced.
// ---------------------------------------------------------------------------
__global__ __launch_bounds__(256) void hs_top(const float* __restrict__ x,
                                              const int* __restrict__ labels,
                                              const float* __restrict__ W,
                                              const float* __restrict__ bias,
                                              float* __restrict__ pcls) {
    __shared__ float xs[8 * NHID];  // 32 KB
    const int t = threadIdx.x;
    const int r0 = blockIdx.x * 8;

    // stage 8 rows, one float4 per thread per row (coalesced, conflict-free)
#pragma unroll
    for (int e = 0; e < 8; e++) {
        ((float4*)(xs + e * NHID))[t] =
            ((const float4*)(x + (size_t)(r0 + e) * NHID))[t];
    }
    __syncthreads();

    const int lane = t & 63;
    const int wave = t >> 6;
    const int e0 = wave * 2;  // 2 rows per wave
    int kc[4];
#pragma unroll
    for (int j = 0; j < 4; j++) kc[j] = min(lane + 64 * j, NCLS - 1);

    float acc[2][4];
#pragma unroll
    for (int i = 0; i < 2; i++)
#pragma unroll
        for (int j = 0; j < 4; j++) acc[i][j] = 0.f;

    const float* xsb = xs + e0 * NHID;
    float wbuf[2][4][4];
    load_w4(wbuf[0], W, kc, NCLS);
    for (int d0 = 0; d0 < NHID; d0 += 8) {
        load_w4(wbuf[1], W + (size_t)(d0 + 4) * NCLS, kc, NCLS);
        fma2x4(acc, xsb, d0, wbuf[0]);
        if (d0 + 8 < NHID) load_w4(wbuf[0], W + (size_t)(d0 + 8) * NCLS, kc, NCLS);
        fma2x4(acc, xsb, d0 + 4, wbuf[1]);
    }

    // fused softmax per row (row lives entirely within this wave)
#pragma unroll
    for (int i = 0; i < 2; i++) {
        float l[4];
#pragma unroll
        for (int j = 0; j < 4; j++) {
            int k = lane + 64 * j;
            l[j] = (k < NCLS) ? acc[i][j] + bias[kc[j]] : -INFINITY;
        }
        float m = fmaxf(fmaxf(l[0], l[1]), fmaxf(l[2], l[3]));
#pragma unroll
        for (int off = 32; off > 0; off >>= 1) m = fmaxf(m, __shfl_xor(m, off, 64));
        float s = 0.f;
#pragma unroll
        for (int j = 0; j < 4; j++) {
            int k = lane + 64 * j;
            if (k < NCLS) s += __expf(l[j] - m);
        }
#pragma unroll
        for (int off = 32; off > 0; off >>= 1) s += __shfl_xor(s, off, 64);
        const int row = r0 + e0 + i;
        const int c = labels[row] / TPC;  // uniform per row
#pragma unroll
        for (int j = 0; j < 4; j++) {
            if (lane + 64 * j == c) pcls[row] = __expf(l[j] - m) / s;
        }
    }
}

// ---------------------------------------------------------------------------
// Kernel 3: bottom level, grouped by class. One block per class; 16 rows per
// pass staged in 64 KB LDS. W_bottom[c] (922 KB) is read once per pass ->
// ~206 MB total HBM. Fused softmax + p_cls*p_word write.
// ---------------------------------------------------------------------------
__global__ __launch_bounds__(256) void hs_bottom(const float* __restrict__ x,
                                                 const float* __restrict__ Wb,
                                                 const float* __restrict__ bb,
                                                 const int* __restrict__ bucket,
                                                 const int* __restrict__ cnt,
                                                 const float* __restrict__ pcls,
                                                 float* __restrict__ out) {
    __shared__ float xs[16 * NHID];  // 64 KB
    const int c = blockIdx.x;
    const int n = cnt[c];
    if (n == 0) return;
    const int t = threadIdx.x;
    const int lane = t & 63;
    const int wave = t >> 6;
    const int e0 = wave * 4;  // 4 rows per wave
    const float* Wc = Wb + (size_t)c * (NHID * TPC);
    int kc[4];
#pragma unroll
    for (int j = 0; j < 4; j++) kc[j] = min(lane + 64 * j, TPC - 1);

    const int npass = (n + 15) >> 4;
    for (int p = 0; p < npass; p++) {
        if (p > 0) __syncthreads();  // previous pass finished reading xs
        // stage up to 16 rows (missing rows -> zeros; their output is unused)
#pragma unroll
        for (int e = 0; e < 16; e++) {
            int idx = p * 16 + e;
            int packed = (idx < n) ? bucket[c * CAP + idx] : -1;
            float4* dst = (float4*)(xs + e * NHID);
            if (packed >= 0) {
                dst[t] = ((const float4*)(x + (size_t)(packed & 0xffff) * NHID))[t];
            } else {
                dst[t] = make_float4(0.f, 0.f, 0.f, 0.f);
            }
        }
        __syncthreads();

        float acc[4][4];
#pragma unroll
        for (int i = 0; i < 4; i++)
#pragma unroll
            for (int j = 0; j < 4; j++) acc[i][j] = 0.f;

        const float* xsb = xs + e0 * NHID;
        float wbuf[2][4][4];
        load_w4(wbuf[0], Wc, kc, TPC);
        for (int d0 = 0; d0 < NHID; d0 += 8) {
            load_w4(wbuf[1], Wc + (size_t)(d0 + 4) * TPC, kc, TPC);
            fma4x4(acc, xsb, d0, wbuf[0]);
            if (d0 + 8 < NHID) load_w4(wbuf[0], Wc + (size_t)(d0 + 8) * TPC, kc, TPC);
            fma4x4(acc, xsb, d0 + 4, wbuf[1]);
        }

        // softmax + output for this wave's 4 rows
#pragma unroll
        for (int i = 0; i < 4; i++) {
            int idx = p * 16 + e0 + i;
            if (idx >= n) continue;  // wave-uniform
            int packed = bucket[c * CAP + idx];
            int row = packed & 0xffff;
            int word = packed >> 16;
            float l[4];
#pragma unroll
            for (int j = 0; j < 4; j++) {
                int k = lane + 64 * j;
                l[j] = (k < TPC) ? acc[i][j] + bb[c * TPC + kc[j]] : -INFINITY;
            }
            float m = fmaxf(fmaxf(l[0], l[1]), fmaxf(l[2], l[3]));
#pragma unroll
            for (int off = 32; off > 0; off >>= 1) m = fmaxf(m, __shfl_xor(m, off, 64));
            float s = 0.f;
#pragma unroll
            for (int j = 0; j < 4; j++) {
                int k = lane + 64 * j;
                if (k < TPC) s += __expf(l[j] - m);
            }
#pragma unroll
            for (int off = 32; off > 0; off >>= 1) s += __shfl_xor(s, off, 64);
#pragma unroll
            for (int j = 0; j < 4; j++) {
                if (lane + 64 * j == word)
                    out[row] = pcls[row] * (__expf(l[j] - m) / s);
            }
        }
    }
}

// ---------------------------------------------------------------------------
extern "C" void kernel_launch(void* const* d_in, const int* in_sizes, int n_in,
                              void* d_out, int out_size, void* d_ws, size_t ws_size,
                              hipStream_t stream) {
    const float* inputs   = (const float*)d_in[0];
    const int*   labels   = (const int*)d_in[1];
    const float* W_top    = (const float*)d_in[2];
    const float* b_top    = (const float*)d_in[3];
    const float* W_bottom = (const float*)d_in[4];
    const float* b_bottom = (const float*)d_in[5];
    float* out = (float*)d_out;

    // ws layout: bucket[NCLS*CAP] ints | cnt[NCLS] ints | pcls[BATCH] floats
    int* bucket = (int*)d_ws;
    int* cnt    = bucket + NCLS * CAP;
    float* pcls = (float*)(cnt + NCLS);

    hs_bucket<<<1, 256, 0, stream>>>(labels, bucket, cnt);
    hs_top<<<BATCH / 8, 256, 0, stream>>>(inputs, labels, W_top, b_top, pcls);
    hs_bottom<<<NCLS, 256, 0, stream>>>(inputs, W_bottom, b_bottom, bucket, cnt,
                                        pcls, out);
}

// Round 2
// 467.364 us; speedup vs baseline: 1.3631x; 1.3631x over previous
//
#include <hip/hip_runtime.h>
#include <math.h>

#define TPC 225
#define NCLS 224
#define NHID 1024
#define BATCH 2048
#define CAP 256  // bucket capacity per class (mean count ~9.1, P(>255) ~ 0)

// ---------------------------------------------------------------------------
// Kernel 1: bucket examples by class. Single block, LDS atomics.
// bucket[c*CAP + i] = (word << 16) | row
// ---------------------------------------------------------------------------
__global__ __launch_bounds__(256) void hs_bucket(const int* __restrict__ labels,
                                                 int* __restrict__ bucket,
                                                 int* __restrict__ cnt) {
    __shared__ int scnt[NCLS];
    const int t = threadIdx.x;
    for (int i = t; i < NCLS; i += 256) scnt[i] = 0;
    __syncthreads();
    for (int b = t; b < BATCH; b += 256) {
        int lab = labels[b];
        int c = lab / TPC;
        int w = lab - c * TPC;
        int pos = atomicAdd(&scnt[c], 1);
        bucket[c * CAP + pos] = (w << 16) | b;
    }
    __syncthreads();
    for (int i = t; i < NCLS; i += 256) cnt[i] = scnt[i];
}

// ---------------------------------------------------------------------------
// Core: R rows x NS slots fused GEMM+softmax for one wave, depth-4 rotating
// prefetch pipeline, no LDS, no barriers. Slot mapping: thread owns columns
// k = lane + 64*j, j in 0..3 (tail clamped/masked). W is [NHID][WS] row-major.
// Group g covers d = 4g..4g+3: 16 strided W dword loads + R broadcast x float4
// loads per group; 16 KB W in flight per wave at depth 4.
// prob[r][j] = softmax probability of slot (lane+64j) for row r.
// ---------------------------------------------------------------------------
template <int R, int WS, int NS>
__device__ __forceinline__ void gemm_softmax_rows(const float* const xrow[R],
                                                  const float* __restrict__ W,
                                                  const float* __restrict__ bias,
                                                  const int lane,
                                                  float prob[R][4]) {
    int kc[4];
#pragma unroll
    for (int j = 0; j < 4; j++) {
        int k = lane + 64 * j;
        kc[j] = (k < NS) ? k : (NS - 1);
    }
    // bias values (4 cold dword loads, overlap with pipeline fill)
    float bs[4];
#pragma unroll
    for (int j = 0; j < 4; j++) bs[j] = bias[kc[j]];

    const float* wj[4];
#pragma unroll
    for (int j = 0; j < 4; j++) wj[j] = W + kc[j];
    const float* xr[R];
#pragma unroll
    for (int r = 0; r < R; r++) xr[r] = xrow[r];

    float wb[4][4][4];   // [buf][dd][j]
    float4 xb[4][R];     // [buf][r]
    float acc[R][4];
#pragma unroll
    for (int r = 0; r < R; r++)
#pragma unroll
        for (int j = 0; j < 4; j++) acc[r][j] = 0.f;

    // ---- prologue: issue groups 0..3 into buffers 0..3 ----
#pragma unroll
    for (int b = 0; b < 4; b++) {
#pragma unroll
        for (int dd = 0; dd < 4; dd++)
#pragma unroll
            for (int j = 0; j < 4; j++) wb[b][dd][j] = wj[j][dd * WS];
#pragma unroll
        for (int r = 0; r < R; r++) xb[b][r] = *(const float4*)(xr[r]);
#pragma unroll
        for (int j = 0; j < 4; j++) wj[j] += 4 * WS;
#pragma unroll
        for (int r = 0; r < R; r++) xr[r] += 4;
    }

    // ---- steady state: 63 iters x 4 groups; compute g, issue g+4 ----
    for (int it = 0; it < 63; it++) {
#pragma unroll
        for (int b = 0; b < 4; b++) {
#pragma unroll
            for (int dd = 0; dd < 4; dd++)
#pragma unroll
                for (int r = 0; r < R; r++) {
                    float xv = ((const float*)&xb[b][r])[dd];
#pragma unroll
                    for (int j = 0; j < 4; j++)
                        acc[r][j] = fmaf(xv, wb[b][dd][j], acc[r][j]);
                }
#pragma unroll
            for (int dd = 0; dd < 4; dd++)
#pragma unroll
                for (int j = 0; j < 4; j++) wb[b][dd][j] = wj[j][dd * WS];
#pragma unroll
            for (int r = 0; r < R; r++) xb[b][r] = *(const float4*)(xr[r]);
#pragma unroll
            for (int j = 0; j < 4; j++) wj[j] += 4 * WS;
#pragma unroll
            for (int r = 0; r < R; r++) xr[r] += 4;
        }
    }

    // ---- epilogue: compute groups 252..255 ----
#pragma unroll
    for (int b = 0; b < 4; b++) {
#pragma unroll
        for (int dd = 0; dd < 4; dd++)
#pragma unroll
            for (int r = 0; r < R; r++) {
                float xv = ((const float*)&xb[b][r])[dd];
#pragma unroll
                for (int j = 0; j < 4; j++)
                    acc[r][j] = fmaf(xv, wb[b][dd][j], acc[r][j]);
            }
    }

    // ---- fused softmax per row (row lives entirely within this wave) ----
#pragma unroll
    for (int r = 0; r < R; r++) {
        float lg[4];
#pragma unroll
        for (int j = 0; j < 4; j++) {
            int k = lane + 64 * j;
            lg[j] = (k < NS) ? acc[r][j] + bs[j] : -INFINITY;
        }
        float m = fmaxf(fmaxf(lg[0], lg[1]), fmaxf(lg[2], lg[3]));
#pragma unroll
        for (int off = 32; off > 0; off >>= 1) m = fmaxf(m, __shfl_xor(m, off, 64));
        float s = 0.f;
        float e[4];
#pragma unroll
        for (int j = 0; j < 4; j++) {
            int k = lane + 64 * j;
            e[j] = (k < NS) ? __expf(lg[j] - m) : 0.f;
            s += e[j];
        }
#pragma unroll
        for (int off = 32; off > 0; off >>= 1) s += __shfl_xor(s, off, 64);
        float inv = 1.f / s;
#pragma unroll
        for (int j = 0; j < 4; j++) prob[r][j] = e[j] * inv;
    }
}

// ---------------------------------------------------------------------------
// Kernel 2: top level. 256 blocks x 8 rows (2 rows/wave). W_top re-read per
// block is L2-served (917 KB fits each XCD's 4 MB L2).
// ---------------------------------------------------------------------------
__global__ __launch_bounds__(256, 1) void hs_top(const float* __restrict__ x,
                                                 const int* __restrict__ labels,
                                                 const float* __restrict__ W,
                                                 const float* __restrict__ bias,
                                                 float* __restrict__ pcls) {
    const int t = threadIdx.x;
    const int lane = t & 63;
    const int wave = t >> 6;
    const int r0 = blockIdx.x * 8 + wave * 2;

    const float* xrow[2] = {x + (size_t)r0 * NHID, x + (size_t)(r0 + 1) * NHID};
    float prob[2][4];
    gemm_softmax_rows<2, NCLS, NCLS>(xrow, W, bias, lane, prob);

#pragma unroll
    for (int r = 0; r < 2; r++) {
        int row = r0 + r;
        int c = labels[row] / TPC;  // wave-uniform per row
#pragma unroll
        for (int j = 0; j < 4; j++)
            if (lane + 64 * j == c) pcls[row] = prob[r][j];
    }
}

// ---------------------------------------------------------------------------
// Kernel 3: bottom level, one block per class, rows/wave templated by count.
// No LDS: x rows are broadcast-loaded in the same pipeline as W.
// ---------------------------------------------------------------------------
template <int R>
__device__ __forceinline__ void bottom_tile(const float* __restrict__ x,
                                            const float* __restrict__ Wc,
                                            const float* __restrict__ bbc,
                                            const int* __restrict__ bucket_c,
                                            const int n, const int base,
                                            const int lane, const int wave,
                                            const float* __restrict__ pcls,
                                            float* __restrict__ out) {
    const int i0 = base + wave * R;
    const float* xrow[R];
    int rowid[R], word[R];
#pragma unroll
    for (int r = 0; r < R; r++) {
        int idx = i0 + r;
        int packed = (idx < n) ? bucket_c[idx] : 0;  // pad rows alias entry 0
        rowid[r] = packed & 0xffff;
        word[r] = packed >> 16;
        xrow[r] = x + (size_t)rowid[r] * NHID;
    }
    float prob[R][4];
    gemm_softmax_rows<R, TPC, TPC>(xrow, Wc, bbc, lane, prob);
#pragma unroll
    for (int r = 0; r < R; r++) {
        if (i0 + r < n) {  // wave-uniform guard
#pragma unroll
            for (int j = 0; j < 4; j++)
                if (lane + 64 * j == word[r])
                    out[rowid[r]] = pcls[rowid[r]] * prob[r][j];
        }
    }
}

__global__ __launch_bounds__(256, 1) void hs_bottom(const float* __restrict__ x,
                                                    const float* __restrict__ Wb,
                                                    const float* __restrict__ bb,
                                                    const int* __restrict__ bucket,
                                                    const int* __restrict__ cnt,
                                                    const float* __restrict__ pcls,
                                                    float* __restrict__ out) {
    const int c = blockIdx.x;
    const int n = cnt[c];
    if (n == 0) return;
    const int t = threadIdx.x;
    const int lane = t & 63;
    const int wave = t >> 6;
    const float* Wc = Wb + (size_t)c * (NHID * TPC);
    const float* bbc = bb + c * TPC;
    const int* bucket_c = bucket + c * CAP;

    int R = (n + 3) >> 2;
    if (R > 8) R = 8;
    const int chunk = 4 * R;
    for (int base = 0; base < n; base += chunk) {
        switch (R) {  // block-uniform branch
            case 1: bottom_tile<1>(x, Wc, bbc, bucket_c, n, base, lane, wave, pcls, out); break;
            case 2: bottom_tile<2>(x, Wc, bbc, bucket_c, n, base, lane, wave, pcls, out); break;
            case 3: bottom_tile<3>(x, Wc, bbc, bucket_c, n, base, lane, wave, pcls, out); break;
            case 4: bottom_tile<4>(x, Wc, bbc, bucket_c, n, base, lane, wave, pcls, out); break;
            case 5: bottom_tile<5>(x, Wc, bbc, bucket_c, n, base, lane, wave, pcls, out); break;
            case 6: bottom_tile<6>(x, Wc, bbc, bucket_c, n, base, lane, wave, pcls, out); break;
            case 7: bottom_tile<7>(x, Wc, bbc, bucket_c, n, base, lane, wave, pcls, out); break;
            default: bottom_tile<8>(x, Wc, bbc, bucket_c, n, base, lane, wave, pcls, out); break;
        }
    }
}

// ---------------------------------------------------------------------------
extern "C" void kernel_launch(void* const* d_in, const int* in_sizes, int n_in,
                              void* d_out, int out_size, void* d_ws, size_t ws_size,
                              hipStream_t stream) {
    const float* inputs   = (const float*)d_in[0];
    const int*   labels   = (const int*)d_in[1];
    const float* W_top    = (const float*)d_in[2];
    const float* b_top    = (const float*)d_in[3];
    const float* W_bottom = (const float*)d_in[4];
    const float* b_bottom = (const float*)d_in[5];
    float* out = (float*)d_out;

    // ws layout: bucket[NCLS*CAP] ints | cnt[NCLS] ints | pcls[BATCH] floats
    int* bucket = (int*)d_ws;
    int* cnt    = bucket + NCLS * CAP;
    float* pcls = (float*)(cnt + NCLS);

    hs_bucket<<<1, 256, 0, stream>>>(labels, bucket, cnt);
    hs_top<<<BATCH / 8, 256, 0, stream>>>(inputs, labels, W_top, b_top, pcls);
    hs_bottom<<<NCLS, 256, 0, stream>>>(inputs, W_bottom, b_bottom, bucket, cnt,
                                        pcls, out);
}